// Round 1
// 137.686 us; speedup vs baseline: 1.0975x; 1.0975x over previous
//
#include <hip/hip_runtime.h>
#include <hip/hip_bf16.h>

// Problem: B=8, T=2048, C=1024, HS=64. fp32 in/out.
// d_in: x[8,2048,1024], Wq[1024,64], Wk[1024,64], Wv[1024,64]
// d_out: [8,2048,64] fp32
// Workspace: q bf16 [16384][64] (pre-scaled log2e/32), k bf16 [16384][64],
//            vT bf16 [8][64][2048] (s-permuted within 64-blocks, see below),
//            Wt bf16 [192][1024]  (~6.4 MB)

#define T_SEQ 2048
#define C_DIM 1024
#define HS 64
#define BT 16384

typedef short s8v __attribute__((ext_vector_type(8)));   // 8 bf16
typedef float f4v __attribute__((ext_vector_type(4)));   // MFMA C/D

__device__ inline unsigned short f2bf(float f) {
  union { float f; unsigned u; } a; a.f = f;
  unsigned r = a.u + 0x7fffu + ((a.u >> 16) & 1u);  // RNE
  return (unsigned short)(r >> 16);
}

// HW-packed f32x2 -> bf16x2 (v_cvt_pk_bf16_f32)
__device__ inline unsigned pk2(float a, float b) {
  union { __hip_bfloat162 h; unsigned u; } c;
  c.h = __float22bfloat162_rn(make_float2(a, b));
  return c.u;
}

__device__ inline s8v cvt8(float4 v0, float4 v1) {
  union { unsigned u[4]; s8v v; } r;
  r.u[0] = pk2(v0.x, v0.y); r.u[1] = pk2(v0.z, v0.w);
  r.u[2] = pk2(v1.x, v1.y); r.u[3] = pk2(v1.z, v1.w);
  return r.v;
}

// async global->LDS, 16 B/lane. LDS base MUST be wave-uniform (SGPR):
// HW writes base + lane*16.
__device__ inline void gl_lds16(const void* g, unsigned char* lds_base,
                                unsigned uniform_byte_off) {
  __builtin_amdgcn_global_load_lds(
      (const __attribute__((address_space(1))) unsigned int*)g,
      (__attribute__((address_space(3))) unsigned int*)(lds_base + uniform_byte_off),
      16, 0, 0);
}

// ------------- Kernel 0: W transpose via LDS (coalesced both ways) -------
__global__ __launch_bounds__(256) void wt_kernel(
    const float* __restrict__ Wq, const float* __restrict__ Wk,
    const float* __restrict__ Wv, unsigned short* __restrict__ wt) {
  __shared__ float tile[64][65];
  const int bid = blockIdx.x;
  const int mat = bid >> 4, kt = bid & 15;
  const float* W = (mat == 0) ? Wq : ((mat == 1) ? Wk : Wv);
  const int t = threadIdx.x;
  const int n = t & 63, kr = t >> 6;
#pragma unroll
  for (int j = 0; j < 16; ++j) {
    const int kl = j * 4 + kr;
    tile[kl][n] = W[(kt * 64 + kl) * HS + n];
  }
  __syncthreads();
  const int n2 = t >> 2, kp = t & 3;
  unsigned int* orow =
      (unsigned int*)(wt + (size_t)(mat * 64 + n2) * C_DIM + kt * 64);
#pragma unroll
  for (int i = 0; i < 8; ++i) {
    const int k0 = kp * 16 + i * 2;
    unsigned int lo = f2bf(tile[k0][n2]);
    unsigned int hi = f2bf(tile[k0 + 1][n2]);
    orow[kp * 8 + i] = lo | (hi << 16);
  }
}

// ------------- Kernel A: QKV projection, async LDS double-buffer ---------
// 512 blocks x 256 threads. M-tile 32; N = 192 (q|k|v); BK = 64.
// V^T store is s-permuted within each 64-block: element (col, t) goes to
// slot j = 4*(t&15) + ((t>>4)&3). The attn PV MFMA uses the same j order
// for its A-operand (P), so the contraction is unchanged.
__global__ __launch_bounds__(256) void qkv_kernel(
    const float* __restrict__ x, const unsigned short* __restrict__ wt,
    unsigned short* __restrict__ qws, unsigned short* __restrict__ kws,
    unsigned short* __restrict__ vtws) {
  __shared__ unsigned char abuf[2][8192];    // 32 rows x 64 fp32 (16 parts)
  __shared__ unsigned char bbuf[2][24576];   // 192 rows x 64 bf16 (8 parts)

  const int tid  = threadIdx.x;
  const int wv   = tid >> 6;
  const int lane = tid & 63;
  const int m    = lane & 15;
  const int quad = lane >> 4;
  const int row0 = blockIdx.x * 32;
  const int mh   = wv >> 1;
  const int ng   = (wv & 1) * 6;

  f4v acc[6];
#pragma unroll
  for (int j = 0; j < 6; ++j) acc[j] = (f4v)0.0f;

  const unsigned au = (unsigned)__builtin_amdgcn_readfirstlane(tid & 192) << 4;

  const float* agp[2];
#pragma unroll
  for (int j = 0; j < 2; ++j) {
    const int s = tid + j * 256;
    const int r = s >> 4, p = (s & 15) ^ (r & 15);
    agp[j] = x + (size_t)(row0 + r) * C_DIM + p * 4;
  }
  const unsigned short* bgp[6];
#pragma unroll
  for (int j = 0; j < 6; ++j) {
    const int s = tid + j * 256;
    const int n = s >> 3, p = (s & 7) ^ (n & 7);
    bgp[j] = wt + (size_t)n * C_DIM + p * 8;
  }

  int aoff[2][2];
#pragma unroll
  for (int c = 0; c < 2; ++c)
#pragma unroll
    for (int t = 0; t < 2; ++t)
      aoff[c][t] = (((mh * 16 + m) * 16) + ((c * 8 + 2 * quad + t) ^ m)) << 4;
  int boff[6][2];
#pragma unroll
  for (int j = 0; j < 6; ++j) {
    const int n = (ng + j) * 16 + m;
#pragma unroll
    for (int c = 0; c < 2; ++c)
      boff[j][c] = (n * 8 + ((c * 4 + quad) ^ (n & 7))) << 4;
  }

#define STAGE(buf, kk)                                                       \
  do {                                                                       \
    _Pragma("unroll") for (int j = 0; j < 2; ++j)                            \
        gl_lds16(agp[j] + (kk), abuf[buf], au + (unsigned)(j * 4096));       \
    _Pragma("unroll") for (int j = 0; j < 6; ++j)                            \
        gl_lds16(bgp[j] + (kk), bbuf[buf], au + (unsigned)(j * 4096));       \
  } while (0)

  STAGE(0, 0);
  for (int it = 0; it < 16; ++it) {
    __syncthreads();                     // stage(it) landed (vmcnt drain)
    if (it < 15) STAGE((it + 1) & 1, (it + 1) * 64);
    const unsigned char* aB = abuf[it & 1];
    const unsigned char* bB = bbuf[it & 1];
#pragma unroll
    for (int c = 0; c < 2; ++c) {
      float4 xa = *(const float4*)(aB + aoff[c][0]);
      float4 xb = *(const float4*)(aB + aoff[c][1]);
      s8v a = cvt8(xa, xb);
#pragma unroll
      for (int j = 0; j < 6; ++j) {
        s8v b = *(const s8v*)(bB + boff[j][c]);
        acc[j] = __builtin_amdgcn_mfma_f32_16x16x32_bf16(a, b, acc[j], 0, 0, 0);
      }
    }
  }
#undef STAGE

  const float qscale = 1.4426950408889634f / 32.0f;  // log2e / sqrt(C)
#pragma unroll
  for (int j = 0; j < 6; ++j) {
    const int nt = ng + j;
    const int mat = nt >> 2, ct = nt & 3;
    const int col = ct * 16 + m;
#pragma unroll
    for (int r = 0; r < 4; ++r) {
      const int row = row0 + mh * 16 + quad * 4 + r;
      const float v = acc[j][r];
      if (mat == 0) {
        qws[row * HS + col] = f2bf(v * qscale);
      } else if (mat == 1) {
        kws[row * HS + col] = f2bf(v);
      } else {
        const int bb = row >> 11, t = row & 2047;
        // s-permuted V^T slot within each 64-block (matches packed P order)
        const int tp = (t & ~63) | (((t & 15) << 2) | ((t >> 4) & 3));
        vtws[(bb * HS + col) * T_SEQ + tp] = f2bf(v);
      }
    }
  }
}

// ------------- Kernel B: causal flash attention, 32 q-rows/block ---------
// grid 512 x 512 threads. XCD pinning: batch = blockIdx.x & 7; LPT
// qi = 63 - (blockIdx.x>>3). 8 waves stride 64-wide s-tiles; each wave
// covers TWO 16-row q-tiles (A: rows r0.., B: rows r0+16..) so K/V frags
// are amortized 2x (L2 traffic 270->135 MB).
// P is stored j-permuted (j = 4*(s&15) + (s>>4)): each lane's 4 values per
// row are j-consecutive -> 2 cvt_pk + one 8B LDS write per row (was 4
// f2bf sequences + 4 b16 writes). V^T is stored with the same permutation.
union __align__(16) AttnSh {
  unsigned short p[8][2][16 * 72];   // per-wave, per-qtile P, 16 rows x 72 u16
  float mo[8][32][64];               // per-wave O partials (merge phase)
};

__global__ __launch_bounds__(512) void attn_kernel(
    const unsigned short* __restrict__ qws, const unsigned short* __restrict__ kws,
    const unsigned short* __restrict__ vtws, float* __restrict__ out) {
  __shared__ AttnSh sh;
  __shared__ float ml[8][32];

  const int tid  = threadIdx.x;
  const int wv   = tid >> 6;
  const int lane = tid & 63;
  const int m    = lane & 15;
  const int quad = lane >> 4;
  const int b    = blockIdx.x & 7;                        // XCD-pinned batch
  const int qi   = (T_SEQ / 32 - 1) - (blockIdx.x >> 3);  // LPT
  const int r0   = qi * 32;
  const int gr0  = b * T_SEQ + r0;

  const unsigned short* qp = qws + (size_t)(gr0 + m) * HS + quad * 8;
  s8v aqA0 = *(const s8v*)qp;
  s8v aqA1 = *(const s8v*)(qp + 32);
  s8v aqB0 = *(const s8v*)(qp + 16 * HS);
  s8v aqB1 = *(const s8v*)(qp + 16 * HS + 32);

  float liA[4] = {0.f, 0.f, 0.f, 0.f};
  float liB[4] = {0.f, 0.f, 0.f, 0.f};
  f4v oA[4], oB[4];
#pragma unroll
  for (int i = 0; i < 4; ++i) { oA[i] = (f4v)0.0f; oB[i] = (f4v)0.0f; }

  const int nst = (r0 + 32 + 63) >> 6;       // causal 64-wide tile bound
  unsigned short* plA = sh.p[wv][0];
  unsigned short* plB = sh.p[wv][1];
  const int qbA = r0 + quad * 4;
  const int qbB = qbA + 16;
  const unsigned short* kbase = kws + (size_t)b * T_SEQ * HS;
  const unsigned short* vbase = vtws + (size_t)b * HS * T_SEQ;

  for (int st = wv; st < nst; st += 8) {
    const int s0 = st * 64;

    s8v kf[4][2];
#pragma unroll
    for (int ns = 0; ns < 4; ++ns) {
      const unsigned short* kp = &kbase[(size_t)(s0 + ns * 16 + m) * HS + quad * 8];
      kf[ns][0] = *(const s8v*)kp;
      kf[ns][1] = *(const s8v*)(kp + 32);
    }
    s8v vf[4][2];
#pragma unroll
    for (int hn = 0; hn < 4; ++hn) {
      const unsigned short* vp = &vbase[(size_t)(hn * 16 + m) * T_SEQ + s0 + quad * 8];
      vf[hn][0] = *(const s8v*)vp;
      vf[hn][1] = *(const s8v*)(vp + 32);
    }

    f4v sa[4], sb[4];
#pragma unroll
    for (int ns = 0; ns < 4; ++ns) {
      f4v t = (f4v)0.0f;
      t = __builtin_amdgcn_mfma_f32_16x16x32_bf16(aqA0, kf[ns][0], t, 0, 0, 0);
      t = __builtin_amdgcn_mfma_f32_16x16x32_bf16(aqA1, kf[ns][1], t, 0, 0, 0);
      sa[ns] = t;
      f4v u = (f4v)0.0f;
      u = __builtin_amdgcn_mfma_f32_16x16x32_bf16(aqB0, kf[ns][0], u, 0, 0, 0);
      u = __builtin_amdgcn_mfma_f32_16x16x32_bf16(aqB1, kf[ns][1], u, 0, 0, 0);
      sb[ns] = u;
    }

    const int sm = s0 + m;
#pragma unroll
    for (int r = 0; r < 4; ++r) {
      const int qr = qbA + r;
      const float p0 = (sm      > qr) ? 0.f : __builtin_amdgcn_exp2f(sa[0][r]);
      const float p1 = (sm + 16 > qr) ? 0.f : __builtin_amdgcn_exp2f(sa[1][r]);
      const float p2 = (sm + 32 > qr) ? 0.f : __builtin_amdgcn_exp2f(sa[2][r]);
      const float p3 = (sm + 48 > qr) ? 0.f : __builtin_amdgcn_exp2f(sa[3][r]);
      liA[r] += (p0 + p1) + (p2 + p3);
      *(uint2*)&plA[(quad * 4 + r) * 72 + m * 4] =
          make_uint2(pk2(p0, p1), pk2(p2, p3));
    }
#pragma unroll
    for (int r = 0; r < 4; ++r) {
      const int qr = qbB + r;
      const float p0 = (sm      > qr) ? 0.f : __builtin_amdgcn_exp2f(sb[0][r]);
      const float p1 = (sm + 16 > qr) ? 0.f : __builtin_amdgcn_exp2f(sb[1][r]);
      const float p2 = (sm + 32 > qr) ? 0.f : __builtin_amdgcn_exp2f(sb[2][r]);
      const float p3 = (sm + 48 > qr) ? 0.f : __builtin_amdgcn_exp2f(sb[3][r]);
      liB[r] += (p0 + p1) + (p2 + p3);
      *(uint2*)&plB[(quad * 4 + r) * 72 + m * 4] =
          make_uint2(pk2(p0, p1), pk2(p2, p3));
    }

    // O += P V : A-frags from LDS (same-wave RAW; DS pipe in-order)
    s8v apA0 = *(const s8v*)&plA[m * 72 + quad * 8];
    s8v apA1 = *(const s8v*)&plA[m * 72 + 32 + quad * 8];
    s8v apB0 = *(const s8v*)&plB[m * 72 + quad * 8];
    s8v apB1 = *(const s8v*)&plB[m * 72 + 32 + quad * 8];
#pragma unroll
    for (int hn = 0; hn < 4; ++hn) {
      oA[hn] = __builtin_amdgcn_mfma_f32_16x16x32_bf16(apA0, vf[hn][0], oA[hn], 0, 0, 0);
      oA[hn] = __builtin_amdgcn_mfma_f32_16x16x32_bf16(apA1, vf[hn][1], oA[hn], 0, 0, 0);
      oB[hn] = __builtin_amdgcn_mfma_f32_16x16x32_bf16(apB0, vf[hn][0], oB[hn], 0, 0, 0);
      oB[hn] = __builtin_amdgcn_mfma_f32_16x16x32_bf16(apB1, vf[hn][1], oB[hn], 0, 0, 0);
    }
  }

#pragma unroll
  for (int r = 0; r < 4; ++r) {
    float s = liA[r];
    s += __shfl_xor(s, 1); s += __shfl_xor(s, 2);
    s += __shfl_xor(s, 4); s += __shfl_xor(s, 8);
    liA[r] = s;
    float u = liB[r];
    u += __shfl_xor(u, 1); u += __shfl_xor(u, 2);
    u += __shfl_xor(u, 4); u += __shfl_xor(u, 8);
    liB[r] = u;
  }

  __syncthreads();   // all waves done with P regions (union reuse)

#pragma unroll
  for (int hn = 0; hn < 4; ++hn)
#pragma unroll
    for (int r = 0; r < 4; ++r) {
      sh.mo[wv][quad * 4 + r][hn * 16 + m] = oA[hn][r];
      sh.mo[wv][16 + quad * 4 + r][hn * 16 + m] = oB[hn][r];
    }
  if (m == 0) {
#pragma unroll
    for (int r = 0; r < 4; ++r) {
      ml[wv][quad * 4 + r] = liA[r];
      ml[wv][16 + quad * 4 + r] = liB[r];
    }
  }
  __syncthreads();

  const int row = tid >> 4, c4 = (tid & 15) * 4;
  float ls = 0.f;
#pragma unroll
  for (int w = 0; w < 8; ++w) ls += ml[w][row];
  const float inv = 1.0f / ls;
  float ax = 0.f, ay = 0.f, az = 0.f, aw = 0.f;
#pragma unroll
  for (int w = 0; w < 8; ++w) {
    float4 v = *(const float4*)&sh.mo[w][row][c4];
    ax += v.x; ay += v.y; az += v.z; aw += v.w;
  }
  float4 res;
  res.x = ax * inv; res.y = ay * inv; res.z = az * inv; res.w = aw * inv;
  *(float4*)&out[(size_t)(gr0 + row) * HS + c4] = res;
}

extern "C" void kernel_launch(void* const* d_in, const int* in_sizes, int n_in,
                              void* d_out, int out_size, void* d_ws, size_t ws_size,
                              hipStream_t stream) {
  const float* x  = (const float*)d_in[0];
  const float* Wq = (const float*)d_in[1];
  const float* Wk = (const float*)d_in[2];
  const float* Wv = (const float*)d_in[3];
  float* out = (float*)d_out;

  unsigned short* qws  = (unsigned short*)d_ws;          // 2 MB
  unsigned short* kws  = qws + (size_t)BT * HS;          // 2 MB
  unsigned short* vtws = kws + (size_t)BT * HS;          // 2 MB
  unsigned short* wt   = vtws + (size_t)BT * HS;         // 384 KB

  wt_kernel<<<dim3(48), dim3(256), 0, stream>>>(Wq, Wk, Wv, wt);
  qkv_kernel<<<dim3(BT / 32), dim3(256), 0, stream>>>(x, wt, qws, kws, vtws);
  attn_kernel<<<dim3(512), dim3(512), 0, stream>>>(qws, kws, vtws, out);
}

// Round 2
// 135.427 us; speedup vs baseline: 1.1158x; 1.0167x over previous
//
#include <hip/hip_runtime.h>
#include <hip/hip_bf16.h>

// Problem: B=8, T=2048, C=1024, HS=64. fp32 in/out.
// d_in: x[8,2048,1024], Wq[1024,64], Wk[1024,64], Wv[1024,64]
// d_out: [8,2048,64] fp32
// Workspace: q bf16 [16384][64] (pre-scaled log2e/32), k bf16 [16384][64],
//            vT bf16 [8][64][2048] (s-permuted within 64-blocks, see below),
//            Wt bf16 [192][1024]  (~6.4 MB)

#define T_SEQ 2048
#define C_DIM 1024
#define HS 64
#define BT 16384

typedef short s8v __attribute__((ext_vector_type(8)));   // 8 bf16
typedef float f4v __attribute__((ext_vector_type(4)));   // MFMA C/D

__device__ inline unsigned short f2bf(float f) {
  union { float f; unsigned u; } a; a.f = f;
  unsigned r = a.u + 0x7fffu + ((a.u >> 16) & 1u);  // RNE
  return (unsigned short)(r >> 16);
}

// HW-packed f32x2 -> bf16x2 (v_cvt_pk_bf16_f32)
__device__ inline unsigned pk2(float a, float b) {
  union { __hip_bfloat162 h; unsigned u; } c;
  c.h = __float22bfloat162_rn(make_float2(a, b));
  return c.u;
}

__device__ inline s8v cvt8(float4 v0, float4 v1) {
  union { unsigned u[4]; s8v v; } r;
  r.u[0] = pk2(v0.x, v0.y); r.u[1] = pk2(v0.z, v0.w);
  r.u[2] = pk2(v1.x, v1.y); r.u[3] = pk2(v1.z, v1.w);
  return r.v;
}

// async global->LDS, 16 B/lane. LDS base MUST be wave-uniform (SGPR):
// HW writes base + lane*16.
__device__ inline void gl_lds16(const void* g, unsigned char* lds_base,
                                unsigned uniform_byte_off) {
  __builtin_amdgcn_global_load_lds(
      (const __attribute__((address_space(1))) unsigned int*)g,
      (__attribute__((address_space(3))) unsigned int*)(lds_base + uniform_byte_off),
      16, 0, 0);
}

// ------------- Kernel 0: W transpose via LDS (coalesced both ways) -------
__global__ __launch_bounds__(256) void wt_kernel(
    const float* __restrict__ Wq, const float* __restrict__ Wk,
    const float* __restrict__ Wv, unsigned short* __restrict__ wt) {
  __shared__ float tile[64][65];
  const int bid = blockIdx.x;
  const int mat = bid >> 4, kt = bid & 15;
  const float* W = (mat == 0) ? Wq : ((mat == 1) ? Wk : Wv);
  const int t = threadIdx.x;
  const int n = t & 63, kr = t >> 6;
#pragma unroll
  for (int j = 0; j < 16; ++j) {
    const int kl = j * 4 + kr;
    tile[kl][n] = W[(kt * 64 + kl) * HS + n];
  }
  __syncthreads();
  const int n2 = t >> 2, kp = t & 3;
  unsigned int* orow =
      (unsigned int*)(wt + (size_t)(mat * 64 + n2) * C_DIM + kt * 64);
#pragma unroll
  for (int i = 0; i < 8; ++i) {
    const int k0 = kp * 16 + i * 2;
    unsigned int lo = f2bf(tile[k0][n2]);
    unsigned int hi = f2bf(tile[k0 + 1][n2]);
    orow[kp * 8 + i] = lo | (hi << 16);
  }
}

// ------------- Kernel A: QKV projection, async LDS double-buffer ---------
// 512 blocks x 256 threads. M-tile 32; N = 192 (q|k|v); BK = 64.
// V^T store is s-permuted within each 64-block: element (col, t) goes to
// slot j = 4*(t&15) + ((t>>4)&3). The attn PV MFMA uses the same j order
// for its A-operand (P), so the contraction is unchanged.
__global__ __launch_bounds__(256) void qkv_kernel(
    const float* __restrict__ x, const unsigned short* __restrict__ wt,
    unsigned short* __restrict__ qws, unsigned short* __restrict__ kws,
    unsigned short* __restrict__ vtws) {
  __shared__ unsigned char abuf[2][8192];    // 32 rows x 64 fp32 (16 parts)
  __shared__ unsigned char bbuf[2][24576];   // 192 rows x 64 bf16 (8 parts)

  const int tid  = threadIdx.x;
  const int wv   = tid >> 6;
  const int lane = tid & 63;
  const int m    = lane & 15;
  const int quad = lane >> 4;
  const int row0 = blockIdx.x * 32;
  const int mh   = wv >> 1;
  const int ng   = (wv & 1) * 6;

  f4v acc[6];
#pragma unroll
  for (int j = 0; j < 6; ++j) acc[j] = (f4v)0.0f;

  const unsigned au = (unsigned)__builtin_amdgcn_readfirstlane(tid & 192) << 4;

  const float* agp[2];
#pragma unroll
  for (int j = 0; j < 2; ++j) {
    const int s = tid + j * 256;
    const int r = s >> 4, p = (s & 15) ^ (r & 15);
    agp[j] = x + (size_t)(row0 + r) * C_DIM + p * 4;
  }
  const unsigned short* bgp[6];
#pragma unroll
  for (int j = 0; j < 6; ++j) {
    const int s = tid + j * 256;
    const int n = s >> 3, p = (s & 7) ^ (n & 7);
    bgp[j] = wt + (size_t)n * C_DIM + p * 8;
  }

  int aoff[2][2];
#pragma unroll
  for (int c = 0; c < 2; ++c)
#pragma unroll
    for (int t = 0; t < 2; ++t)
      aoff[c][t] = (((mh * 16 + m) * 16) + ((c * 8 + 2 * quad + t) ^ m)) << 4;
  int boff[6][2];
#pragma unroll
  for (int j = 0; j < 6; ++j) {
    const int n = (ng + j) * 16 + m;
#pragma unroll
    for (int c = 0; c < 2; ++c)
      boff[j][c] = (n * 8 + ((c * 4 + quad) ^ (n & 7))) << 4;
  }

#define STAGE(buf, kk)                                                       \
  do {                                                                       \
    _Pragma("unroll") for (int j = 0; j < 2; ++j)                            \
        gl_lds16(agp[j] + (kk), abuf[buf], au + (unsigned)(j * 4096));       \
    _Pragma("unroll") for (int j = 0; j < 6; ++j)                            \
        gl_lds16(bgp[j] + (kk), bbuf[buf], au + (unsigned)(j * 4096));       \
  } while (0)

  STAGE(0, 0);
  for (int it = 0; it < 16; ++it) {
    __syncthreads();                     // stage(it) landed (vmcnt drain)
    if (it < 15) STAGE((it + 1) & 1, (it + 1) * 64);
    const unsigned char* aB = abuf[it & 1];
    const unsigned char* bB = bbuf[it & 1];
#pragma unroll
    for (int c = 0; c < 2; ++c) {
      float4 xa = *(const float4*)(aB + aoff[c][0]);
      float4 xb = *(const float4*)(aB + aoff[c][1]);
      s8v a = cvt8(xa, xb);
#pragma unroll
      for (int j = 0; j < 6; ++j) {
        s8v b = *(const s8v*)(bB + boff[j][c]);
        acc[j] = __builtin_amdgcn_mfma_f32_16x16x32_bf16(a, b, acc[j], 0, 0, 0);
      }
    }
  }
#undef STAGE

  const float qscale = 1.4426950408889634f / 32.0f;  // log2e / sqrt(C)
#pragma unroll
  for (int j = 0; j < 6; ++j) {
    const int nt = ng + j;
    const int mat = nt >> 2, ct = nt & 3;
    const int col = ct * 16 + m;
#pragma unroll
    for (int r = 0; r < 4; ++r) {
      const int row = row0 + mh * 16 + quad * 4 + r;
      const float v = acc[j][r];
      if (mat == 0) {
        qws[row * HS + col] = f2bf(v * qscale);
      } else if (mat == 1) {
        kws[row * HS + col] = f2bf(v);
      } else {
        const int bb = row >> 11, t = row & 2047;
        // s-permuted V^T slot within each 64-block (matches packed P order)
        const int tp = (t & ~63) | (((t & 15) << 2) | ((t >> 4) & 3));
        vtws[(bb * HS + col) * T_SEQ + tp] = f2bf(v);
      }
    }
  }
}

// ------------- Kernel B: causal flash attention, 64 q-rows/block ---------
// grid 256 x 512 threads. XCD pinning: batch = blockIdx.x & 7 (one batch
// per XCD; its K/V = 512 KB stays L2-resident). Block pr = blockIdx.x>>3
// handles COMPLEMENTARY q-groups pr and 63-pr: per-block s-tile work
// nstS + nstB == 33 for every pr -> perfect static balance at 1 block/CU.
// Each wave holds 4 q-tiles (0,1 = rows rS..rS+32; 2,3 = rows rB..rB+32).
// For s-tiles st < nstS all 4 tiles share one K/V fragment load (64 MFMA
// per 16 KB); beyond, only tiles 2,3 (32 MFMA per 16 KB).
// P is stored j-permuted (j = 4*(s&15) + (s>>4)): each lane's 4 values per
// row are j-consecutive -> 2 cvt_pk + one 8B LDS write per row. V^T is
// stored with the same permutation by the qkv epilogue.
union __align__(16) AttnSh {
  unsigned short p[8][4][16 * 72];   // per-wave, per-qtile P: 73728 B
  float mo[8][32][64];               // per-wave O partials (merge): 65536 B
};

__global__ __launch_bounds__(512) void attn_kernel(
    const unsigned short* __restrict__ qws, const unsigned short* __restrict__ kws,
    const unsigned short* __restrict__ vtws, float* __restrict__ out) {
  __shared__ AttnSh sh;
  __shared__ float ml[8][32];

  const int tid  = threadIdx.x;
  const int wv   = tid >> 6;
  const int lane = tid & 63;
  const int m    = lane & 15;
  const int quad = lane >> 4;
  const int b    = blockIdx.x & 7;          // XCD-pinned batch
  const int pr   = blockIdx.x >> 3;         // 0..31 complementary pair id
  const int rS   = pr * 32;
  const int rB   = (63 - pr) * 32;
  const int grS  = b * T_SEQ + rS;
  const int grB  = b * T_SEQ + rB;

  const unsigned short* qpS = qws + (size_t)(grS + m) * HS + quad * 8;
  const unsigned short* qpB = qws + (size_t)(grB + m) * HS + quad * 8;
  s8v aq[4][2];
  aq[0][0] = *(const s8v*)qpS;
  aq[0][1] = *(const s8v*)(qpS + 32);
  aq[1][0] = *(const s8v*)(qpS + 16 * HS);
  aq[1][1] = *(const s8v*)(qpS + 16 * HS + 32);
  aq[2][0] = *(const s8v*)qpB;
  aq[2][1] = *(const s8v*)(qpB + 32);
  aq[3][0] = *(const s8v*)(qpB + 16 * HS);
  aq[3][1] = *(const s8v*)(qpB + 16 * HS + 32);

  float li[4][4];
  f4v o[4][4];
#pragma unroll
  for (int t = 0; t < 4; ++t)
#pragma unroll
    for (int i = 0; i < 4; ++i) { li[t][i] = 0.f; o[t][i] = (f4v)0.0f; }

  const int nstS = (rS + 32 + 63) >> 6;   // causal bound, small group
  const int nstB = (rB + 32 + 63) >> 6;   // causal bound, big group
  const int qb0 = rS + quad * 4;
  const int qb1 = qb0 + 16;
  const int qb2 = rB + quad * 4;
  const int qb3 = qb2 + 16;
  const unsigned short* kbase = kws + (size_t)b * T_SEQ * HS;
  const unsigned short* vbase = vtws + (size_t)b * HS * T_SEQ;

// QK^T + mask + exp2 + packed P store for q-tile t (literal t only!)
#define QKT(t, qbase)                                                        \
  {                                                                          \
    f4v s_[4];                                                               \
    _Pragma("unroll") for (int ns = 0; ns < 4; ++ns) {                       \
      f4v u_ = (f4v)0.0f;                                                    \
      u_ = __builtin_amdgcn_mfma_f32_16x16x32_bf16(aq[t][0], kf[ns][0], u_, 0, 0, 0); \
      u_ = __builtin_amdgcn_mfma_f32_16x16x32_bf16(aq[t][1], kf[ns][1], u_, 0, 0, 0); \
      s_[ns] = u_;                                                           \
    }                                                                        \
    _Pragma("unroll") for (int r = 0; r < 4; ++r) {                          \
      const int qr = (qbase) + r;                                            \
      const float p0 = (sm      > qr) ? 0.f : __builtin_amdgcn_exp2f(s_[0][r]); \
      const float p1 = (sm + 16 > qr) ? 0.f : __builtin_amdgcn_exp2f(s_[1][r]); \
      const float p2 = (sm + 32 > qr) ? 0.f : __builtin_amdgcn_exp2f(s_[2][r]); \
      const float p3 = (sm + 48 > qr) ? 0.f : __builtin_amdgcn_exp2f(s_[3][r]); \
      li[t][r] += (p0 + p1) + (p2 + p3);                                     \
      *(uint2*)&sh.p[wv][t][(quad * 4 + r) * 72 + m * 4] =                   \
          make_uint2(pk2(p0, p1), pk2(p2, p3));                              \
    }                                                                        \
  }

// O += P V for q-tile t (same-wave DS RAW; DS pipe in-order)
#define PVT(t)                                                               \
  {                                                                          \
    const unsigned short* pl_ = sh.p[wv][t];                                 \
    s8v a0_ = *(const s8v*)&pl_[m * 72 + quad * 8];                          \
    s8v a1_ = *(const s8v*)&pl_[m * 72 + 32 + quad * 8];                     \
    _Pragma("unroll") for (int hn = 0; hn < 4; ++hn) {                       \
      o[t][hn] = __builtin_amdgcn_mfma_f32_16x16x32_bf16(a0_, vf[hn][0], o[t][hn], 0, 0, 0); \
      o[t][hn] = __builtin_amdgcn_mfma_f32_16x16x32_bf16(a1_, vf[hn][1], o[t][hn], 0, 0, 0); \
    }                                                                        \
  }

  for (int st = wv; st < nstB; st += 8) {
    const int s0 = st * 64;

    s8v kf[4][2];
#pragma unroll
    for (int ns = 0; ns < 4; ++ns) {
      const unsigned short* kp = &kbase[(size_t)(s0 + ns * 16 + m) * HS + quad * 8];
      kf[ns][0] = *(const s8v*)kp;
      kf[ns][1] = *(const s8v*)(kp + 32);
    }
    s8v vf[4][2];
#pragma unroll
    for (int hn = 0; hn < 4; ++hn) {
      const unsigned short* vp = &vbase[(size_t)(hn * 16 + m) * T_SEQ + s0 + quad * 8];
      vf[hn][0] = *(const s8v*)vp;
      vf[hn][1] = *(const s8v*)(vp + 32);
    }

    const int sm = s0 + m;
    const bool low = (st < nstS);   // wave-uniform branch
    if (low) { QKT(0, qb0); QKT(1, qb1); }
    QKT(2, qb2);
    QKT(3, qb3);
    if (low) { PVT(0); PVT(1); }
    PVT(2);
    PVT(3);
  }
#undef QKT
#undef PVT

  // reduce li over the 16 s-lanes (m) of each quad-row group
#pragma unroll
  for (int t = 0; t < 4; ++t)
#pragma unroll
    for (int r = 0; r < 4; ++r) {
      float s = li[t][r];
      s += __shfl_xor(s, 1); s += __shfl_xor(s, 2);
      s += __shfl_xor(s, 4); s += __shfl_xor(s, 8);
      li[t][r] = s;
    }

  // merge in two passes (tiles 0,1 -> rows rS..; tiles 2,3 -> rows rB..)
  const int row = tid >> 4, c4 = (tid & 15) * 4;
#pragma unroll
  for (int ps = 0; ps < 2; ++ps) {
    __syncthreads();   // P region / previous pass reads complete
#pragma unroll
    for (int hn = 0; hn < 4; ++hn)
#pragma unroll
      for (int r = 0; r < 4; ++r) {
        sh.mo[wv][quad * 4 + r][hn * 16 + m]      = o[2 * ps][hn][r];
        sh.mo[wv][16 + quad * 4 + r][hn * 16 + m] = o[2 * ps + 1][hn][r];
      }
    if (m == 0) {
#pragma unroll
      for (int r = 0; r < 4; ++r) {
        ml[wv][quad * 4 + r]      = li[2 * ps][r];
        ml[wv][16 + quad * 4 + r] = li[2 * ps + 1][r];
      }
    }
    __syncthreads();

    float ls = 0.f;
#pragma unroll
    for (int w = 0; w < 8; ++w) ls += ml[w][row];
    const float inv = 1.0f / ls;
    float ax = 0.f, ay = 0.f, az = 0.f, aw = 0.f;
#pragma unroll
    for (int w = 0; w < 8; ++w) {
      float4 v = *(const float4*)&sh.mo[w][row][c4];
      ax += v.x; ay += v.y; az += v.z; aw += v.w;
    }
    const int gr = ps ? grB : grS;
    float4 res;
    res.x = ax * inv; res.y = ay * inv; res.z = az * inv; res.w = aw * inv;
    *(float4*)&out[(size_t)(gr + row) * HS + c4] = res;
  }
}

extern "C" void kernel_launch(void* const* d_in, const int* in_sizes, int n_in,
                              void* d_out, int out_size, void* d_ws, size_t ws_size,
                              hipStream_t stream) {
  const float* x  = (const float*)d_in[0];
  const float* Wq = (const float*)d_in[1];
  const float* Wk = (const float*)d_in[2];
  const float* Wv = (const float*)d_in[3];
  float* out = (float*)d_out;

  unsigned short* qws  = (unsigned short*)d_ws;          // 2 MB
  unsigned short* kws  = qws + (size_t)BT * HS;          // 2 MB
  unsigned short* vtws = kws + (size_t)BT * HS;          // 2 MB
  unsigned short* wt   = vtws + (size_t)BT * HS;         // 384 KB

  wt_kernel<<<dim3(48), dim3(256), 0, stream>>>(Wq, Wk, Wv, wt);
  qkv_kernel<<<dim3(BT / 32), dim3(256), 0, stream>>>(x, wt, qws, kws, vtws);
  attn_kernel<<<dim3(256), dim3(512), 0, stream>>>(qws, kws, vtws, out);
}